// Round 12
// baseline (385.704 us; speedup 1.0000x reference)
//
#include <hip/hip_runtime.h>
#include <hip/hip_bf16.h>
#include <math.h>

// Problem constants
#define NB   4
#define NQL  2048
#define NKVL 2048
#define HN   8
#define DQK  160    // qk feature dim
#define DV   288    // v feature dim
#define QT   256    // q rows per block (8 waves x 32)
#define KTL  64     // kv per tile
#define KLP  168    // K LDS row stride (bf16 elems) = 336 B = 21 x 16B chunks

#define SCALE 0.07905694150420949f   // 1/sqrt(160), folded into Q

typedef __attribute__((ext_vector_type(8)))  short short8;
typedef __attribute__((ext_vector_type(4)))  float f32x4;
typedef __attribute__((ext_vector_type(16))) float f32x16;

__constant__ int c_grade[16] = {0,1,1,1,1,2,2,2,2,2,2,3,3,3,3,4};
__constant__ int c_inner[8]  = {0,2,3,4,8,9,10,14};
__constant__ int c_esrc[16]  = {-1,0,-1,-1,-1,2,3,4,-1,-1,-1,8,9,10,-1,14};
__constant__ int c_ey[16]    = {0,5,0,0,0,6,6,6,0,0,0,7,7,7,0,8};

__device__ __forceinline__ ushort f2bf(float v) {
  __hip_bfloat16 h = __float2bfloat16(v);
  union { __hip_bfloat16 b; ushort u; } cv; cv.b = h; return cv.u;
}

// async global->LDS, 16B per lane; LDS dest = uniform base + lane*16
__device__ __forceinline__ void gload16(const void* g, void* l) {
  __builtin_amdgcn_global_load_lds(
      (const __attribute__((address_space(1))) unsigned int*)g,
      (__attribute__((address_space(3))) unsigned int*)l, 16, 0, 0);
}

// ---------------- K/V projection (weight-stationary, 8 pos/block) ----------------
#define KWMV   0
#define KS2MV  2304
#define KMV2S  2816
#define KS2S   3328
#define KBMV   4352
#define KBS    4368
#define VWMV   4400
#define VS2MV  6704
#define VMV2S  7216
#define VS2S   7728
#define VBMV   8752
#define VBS    8768
#define WLSZ   8800
#define XSTR   289   // pos stride in xL
#define OSTR   456   // pos stride in oL (ushort)
#define KVPOS  8

__device__ __forceinline__ void kv_accum(const float* wL, const float* xL,
                                         int f, float acc[KVPOS]) {
  if (f < 160) {
    if (f < 128) {                      // K mv-feature
      int c = f >> 3, a = c_inner[f & 7], y = c_grade[a];
      float bias = (a == 0) ? wL[KBMV + c] : 0.f;
#pragma unroll
      for (int p = 0; p < KVPOS; p++) acc[p] = bias;
      for (int ci = 0; ci < 16; ci++) {
        float w = wL[KWMV + (c*16 + ci)*9 + y];
#pragma unroll
        for (int p = 0; p < KVPOS; p++) acc[p] += w * xL[p*XSTR + ci*16 + a];
      }
      if (a == 0) {
        for (int i2 = 0; i2 < 32; i2++) {
          float w = wL[KS2MV + c*32 + i2];
#pragma unroll
          for (int p = 0; p < KVPOS; p++) acc[p] += w * xL[p*XSTR + 256 + i2];
        }
      }
    } else {                            // K scalar
      int si = f - 128;
      float bias = wL[KBS + si];
#pragma unroll
      for (int p = 0; p < KVPOS; p++) acc[p] = bias;
      for (int ci = 0; ci < 16; ci++) {
        float w = wL[KMV2S + si*16 + ci];
#pragma unroll
        for (int p = 0; p < KVPOS; p++) acc[p] += w * xL[p*XSTR + ci*16];
      }
      for (int i2 = 0; i2 < 32; i2++) {
        float w = wL[KS2S + si*32 + i2];
#pragma unroll
        for (int p = 0; p < KVPOS; p++) acc[p] += w * xL[p*XSTR + 256 + i2];
      }
    }
  } else {
    int g = f - 160;
    if (g < 256) {                      // V mv-feature
      int c = g >> 4, a = g & 15, y = c_grade[a];
      float bias = (a == 0) ? wL[VBMV + c] : 0.f;
#pragma unroll
      for (int p = 0; p < KVPOS; p++) acc[p] = bias;
      for (int ci = 0; ci < 16; ci++) {
        float w = wL[VWMV + (c*16 + ci)*9 + y];
#pragma unroll
        for (int p = 0; p < KVPOS; p++) acc[p] += w * xL[p*XSTR + ci*16 + a];
      }
      int sa = c_esrc[a];
      if (sa >= 0) {
        int ey = c_ey[a];
        for (int ci = 0; ci < 16; ci++) {
          float w = wL[VWMV + (c*16 + ci)*9 + ey];
#pragma unroll
          for (int p = 0; p < KVPOS; p++) acc[p] += w * xL[p*XSTR + ci*16 + sa];
        }
      }
      if (a == 0) {
        for (int i2 = 0; i2 < 32; i2++) {
          float w = wL[VS2MV + c*32 + i2];
#pragma unroll
          for (int p = 0; p < KVPOS; p++) acc[p] += w * xL[p*XSTR + 256 + i2];
        }
      }
    } else {                            // V scalar
      int si = g - 256;
      float bias = wL[VBS + si];
#pragma unroll
      for (int p = 0; p < KVPOS; p++) acc[p] = bias;
      for (int ci = 0; ci < 16; ci++) {
        float w = wL[VMV2S + si*16 + ci];
#pragma unroll
        for (int p = 0; p < KVPOS; p++) acc[p] += w * xL[p*XSTR + ci*16];
      }
      for (int i2 = 0; i2 < 32; i2++) {
        float w = wL[VS2S + si*32 + i2];
#pragma unroll
        for (int p = 0; p < KVPOS; p++) acc[p] += w * xL[p*XSTR + 256 + i2];
      }
    }
  }
}

__global__ __launch_bounds__(256) void proj_kv_kernel(
    const float* __restrict__ mv_kv, const float* __restrict__ s_kv,
    const float* __restrict__ kw_mv, const float* __restrict__ kw_s2mv, const float* __restrict__ kb_mv,
    const float* __restrict__ kw_mv2s, const float* __restrict__ kw_s2s, const float* __restrict__ kb_s,
    const float* __restrict__ vw_mv, const float* __restrict__ vw_s2mv, const float* __restrict__ vb_mv,
    const float* __restrict__ vw_mv2s, const float* __restrict__ vw_s2s, const float* __restrict__ vb_s,
    ushort* __restrict__ Kf, ushort* __restrict__ VfT)
{
  __shared__ float wL[WLSZ];
  __shared__ float xL[KVPOS*XSTR];
  int t = threadIdx.x;
  for (int i = t; i < 2304; i += 256) wL[KWMV + i] = kw_mv[i];
  for (int i = t; i < 512;  i += 256) wL[KS2MV + i] = kw_s2mv[i];
  for (int i = t; i < 512;  i += 256) wL[KMV2S + i] = kw_mv2s[i];
  for (int i = t; i < 1024; i += 256) wL[KS2S + i] = kw_s2s[i];
  if (t < 16) wL[KBMV + t] = kb_mv[t];
  if (t < 32) wL[KBS + t] = kb_s[t];
  for (int i = t; i < 2304; i += 256) wL[VWMV + i] = vw_mv[i];
  for (int i = t; i < 512;  i += 256) wL[VS2MV + i] = vw_s2mv[i];
  for (int i = t; i < 512;  i += 256) wL[VMV2S + i] = vw_mv2s[i];
  for (int i = t; i < 1024; i += 256) wL[VS2S + i] = vw_s2s[i];
  if (t < 16) wL[VBMV + t] = vb_mv[t];
  if (t < 32) wL[VBS + t] = vb_s[t];

  int p0 = blockIdx.x * KVPOS;
  for (int i = t; i < KVPOS*256; i += 256) {
    int p = i >> 8, c = i & 255;
    xL[p*XSTR + c] = mv_kv[(size_t)(p0 + p)*256 + c];
  }
  if (t < KVPOS*32) {
    int p = t >> 5, c = t & 31;
    xL[p*XSTR + 256 + c] = s_kv[(size_t)(p0 + p)*32 + c];
  }
  __syncthreads();

  float acc0[KVPOS], acc1[KVPOS];
  kv_accum(wL, xL, t, acc0);
  if (t < 192) kv_accum(wL, xL, 256 + t, acc1);
  __syncthreads();

  ushort* oL = (ushort*)xL;
#pragma unroll
  for (int p = 0; p < KVPOS; p++) oL[p*OSTR + t] = f2bf(acc0[p]);
  if (t < 192) {
#pragma unroll
    for (int p = 0; p < KVPOS; p++) oL[p*OSTR + 256 + t] = f2bf(acc1[p]);
  }
  __syncthreads();

  int b = p0 >> 11, kv0 = p0 & 2047;
  // K: 8 pos x 80 uint = 640
  for (int it = 0; it < 3; it++) {
    int j = t + it*256;
    if (j < KVPOS*80) {
      int p = j / 80, fp = j - p*80;
      uint u = (uint)oL[p*OSTR + 2*fp] | ((uint)oL[p*OSTR + 2*fp + 1] << 16);
      *(uint*)(Kf + (size_t)(p0 + p)*DQK + 2*fp) = u;
    }
  }
  // V^T with chunk-XOR baked into the GLOBAL layout
  for (int it = 0; it < 5; it++) {
    int j = t + it*256;
    if (j < DV*(KVPOS/2)) {
      int g = j >> 2, pp = j & 3;
      uint u = (uint)oL[(2*pp)*OSTR + 160 + g] | ((uint)oL[(2*pp+1)*OSTR + 160 + g] << 16);
      int kv = kv0 + 2*pp;
      int pos = (kv & ~63) + ((((kv >> 3) & 7) ^ (g & 7)) << 3) + (kv & 7);
      *(uint*)(VfT + ((size_t)b*DV + g)*NKVL + pos) = u;
    }
  }
}

// ---------------- fused weight-prep (O transpose + Q transpose) ----------------
#define OWT_SZ 34816
#define QWT_MV 0
#define QWT_S  20480
#define QBT    61440
#define QWT_SZ 62720
__global__ __launch_bounds__(256) void prep_w_kernel(
    const float* __restrict__ ow_mv, const float* __restrict__ ow_s2mv,
    const float* __restrict__ ow_mv2s, const float* __restrict__ ow_s2s,
    float* __restrict__ owT,
    const float* __restrict__ qw_mv, const float* __restrict__ qw_s2mv, const float* __restrict__ qb_mv,
    const float* __restrict__ qw_mv2s, const float* __restrict__ qw_s2s, const float* __restrict__ qb_s,
    float* __restrict__ qwT)
{
  int i = blockIdx.x*256 + threadIdx.x;
  if (i < OWT_SZ) {
    if (i < 18432) {
      int y = i / 2048, r = i & 2047, ch = r >> 4, o = r & 15;
      owT[i] = ow_mv[(size_t)(o*128 + ch)*9 + y];
    } else if (i < 22528) {
      int r = i - 18432, jj = r >> 4, o = r & 15;
      owT[i] = ow_s2mv[o*256 + jj];
    } else if (i < 26624) {
      int r = i - 22528, ch = r >> 5, si = r & 31;
      owT[i] = ow_mv2s[si*128 + ch];
    } else {
      int r = i - 26624, jj = r >> 5, si = r & 31;
      owT[i] = ow_s2s[si*256 + jj];
    }
    return;
  }
  int j = i - OWT_SZ;
  if (j >= QWT_SZ) return;
  if (j < QWT_S) {
    int ci = j / 1280, r = j - ci*1280, h = r / 160, f0 = r - h*160;
    float v;
    if (f0 < 128) {
      int c = f0 >> 3, a = c_inner[f0 & 7], y = c_grade[a];
      v = qw_mv[((c*HN + h)*16 + ci)*9 + y];
    } else {
      v = qw_mv2s[((f0 - 128)*HN + h)*16 + ci];
    }
    qwT[j] = v;
  } else if (j < QBT) {
    int k = j - QWT_S;
    int i2 = k / 1280, r = k - i2*1280, h = r / 160, f0 = r - h*160;
    float v;
    if (f0 < 128) {
      int c = f0 >> 3, a = c_inner[f0 & 7];
      v = (a == 0) ? qw_s2mv[(c*HN + h)*32 + i2] : 0.f;
    } else {
      v = qw_s2s[((f0 - 128)*HN + h)*32 + i2];
    }
    qwT[j] = v;
  } else {
    int r = j - QBT, h = r / 160, f0 = r - h*160;
    float v;
    if (f0 < 128) {
      int c = f0 >> 3, a = c_inner[f0 & 7];
      v = (a == 0) ? qb_mv[c*HN + h] : 0.f;
    } else {
      v = qb_s[(f0 - 128)*HN + h];
    }
    qwT[j] = v;
  }
}

// ---------------- Q projection (coalesced transposed weights, 8 pos/block) ----------------
#define QPOS 8
__global__ __launch_bounds__(320) void proj_q_kernel(
    const float* __restrict__ mv_q, const float* __restrict__ s_q,
    const float* __restrict__ qwT,
    ushort* __restrict__ Qf)
{
  __shared__ float xL[QPOS*XSTR];
  int t = threadIdx.x;
  int p0 = blockIdx.x * QPOS;
  for (int i = t; i < QPOS*256; i += 320) {
    int p = i >> 8, c = i & 255;
    xL[p*XSTR + c] = mv_q[(size_t)(p0 + p)*256 + c];
  }
  if (t < QPOS*32) {
    int p = t >> 5, c = t & 31;
    xL[p*XSTR + 256 + c] = s_q[(size_t)(p0 + p)*32 + c];
  }
  __syncthreads();

  int f0 = t % 160;
  int h0 = t / 160;                      // heads h0, h0+2, h0+4, h0+6
  int a = (f0 < 128) ? c_inner[f0 & 7] : 0;

  float acc[4][QPOS];
#pragma unroll
  for (int k = 0; k < 4; k++) {
    float bv = qwT[QBT + (h0 + 2*k)*160 + f0];
#pragma unroll
    for (int p = 0; p < QPOS; p++) acc[k][p] = bv;
  }
  for (int ci = 0; ci < 16; ci++) {
    float w0 = qwT[QWT_MV + (ci*HN + h0    )*160 + f0];
    float w1 = qwT[QWT_MV + (ci*HN + h0 + 2)*160 + f0];
    float w2 = qwT[QWT_MV + (ci*HN + h0 + 4)*160 + f0];
    float w3 = qwT[QWT_MV + (ci*HN + h0 + 6)*160 + f0];
#pragma unroll
    for (int p = 0; p < QPOS; p++) {
      float xv = xL[p*XSTR + ci*16 + a];
      acc[0][p] += w0*xv; acc[1][p] += w1*xv;
      acc[2][p] += w2*xv; acc[3][p] += w3*xv;
    }
  }
  for (int i2 = 0; i2 < 32; i2++) {
    float w0 = qwT[QWT_S + (i2*HN + h0    )*160 + f0];
    float w1 = qwT[QWT_S + (i2*HN + h0 + 2)*160 + f0];
    float w2 = qwT[QWT_S + (i2*HN + h0 + 4)*160 + f0];
    float w3 = qwT[QWT_S + (i2*HN + h0 + 6)*160 + f0];
#pragma unroll
    for (int p = 0; p < QPOS; p++) {
      float xv = xL[p*XSTR + 256 + i2];
      acc[0][p] += w0*xv; acc[1][p] += w1*xv;
      acc[2][p] += w2*xv; acc[3][p] += w3*xv;
    }
  }

  int b = p0 >> 11, q0 = p0 & 2047;
#pragma unroll
  for (int k = 0; k < 4; k++) {
    int h = h0 + 2*k;
    ushort* qdst = Qf + ((size_t)(b*HN + h)*NQL + q0)*DQK + f0;
#pragma unroll
    for (int p = 0; p < QPOS; p++)
      qdst[p*DQK] = f2bf(acc[k][p] * SCALE);
  }
}

// ---------------- MFMA flash attention (unchanged from round 11) ----------------
__global__ __launch_bounds__(512, 2) void attn_kernel(
    const ushort* __restrict__ Kf,   // [b][2048][160] row-major
    const ushort* __restrict__ VfT,  // [b][288][2048] chunk-XOR pre-baked
    const ushort* __restrict__ Qf,   // [bh][2048][160] (scaled)
    float* __restrict__ Hf)          // [b][q][h][288]
{
  __shared__ ushort kL[2][KTL*KLP];
  __shared__ ushort vtL[2][DV*KTL];

  const int NT = NQL/QT;             // 8; grid = 256 blocks (1/CU)
  int bid = blockIdx.x;
  int swz = (bid & 7) * 32 + (bid >> 3);
  int bh = swz / NT;
  int qt = swz - bh*NT;
  int b = bh >> 3, h = bh & 7;
  int t = threadIdx.x, w = t >> 6, l = t & 63;
  int ql = l & 31, hb = l >> 5;

  const ushort* kb = Kf  + (size_t)b*NKVL*DQK;
  const ushort* vb = VfT + (size_t)b*DV*NKVL;

  const ushort* qrow = Qf + ((size_t)bh*NQL + (size_t)qt*QT + w*32 + ql)*DQK + hb*8;
  short8 qf[10];
#pragma unroll
  for (int ks = 0; ks < 10; ks++)
    qf[ks] = *(const short8*)(qrow + ks*16);

  f32x16 oA[9];
#pragma unroll
  for (int i = 0; i < 9; i++) oA[i] = (f32x16)(0.f);
  float m = -INFINITY, lsum = 0.f;

#define STAGE(KT, BUF) do {                                            \
    const ushort* kg_ = kb + (size_t)(KT)*KTL*DQK;                     \
    char* kd_ = (char*)&kL[BUF][0];                                    \
    for (int c_ = w; c_ < 21; c_ += 8) {                               \
      int off_ = c_*1024 + l*16;                                       \
      int row_ = off_ / 336;                                           \
      int bc_  = off_ - row_*336;                                      \
      const ushort* ga_ = kg_ + row_*DQK + ((bc_ < 320) ? (bc_ >> 1) : 0); \
      gload16(ga_, kd_ + c_*1024);                                     \
    }                                                                  \
    const ushort* vg_ = vb + (size_t)(KT)*KTL;                         \
    char* vd_ = (char*)&vtL[BUF][0];                                   \
    for (int c_ = w; c_ < 36; c_ += 8) {                               \
      int off_ = c_*1024 + l*16;                                       \
      int d_  = off_ >> 7;                                             \
      int bc_ = off_ & 127;                                            \
      const ushort* ga_ = vg_ + (size_t)d_*NKVL + (bc_ >> 1);          \
      gload16(ga_, vd_ + c_*1024);                                     \
    }                                                                  \
  } while (0)

  STAGE(0, 0);
  __syncthreads();

  for (int kt = 0; kt < NKVL/KTL; kt++) {
    int cur = kt & 1;
    if (kt + 1 < NKVL/KTL) STAGE(kt + 1, cur ^ 1);

    const ushort* kbuf  = &kL[cur][0];
    const ushort* vtbuf = &vtL[cur][0];

    f32x16 sA[2];
    __builtin_amdgcn_s_setprio(1);
#pragma unroll
    for (int kvb = 0; kvb < 2; kvb++) {
      sA[kvb] = (f32x16)(0.f);
      const ushort* krow = kbuf + (ql + 32*kvb)*KLP + hb*8;
#pragma unroll
      for (int ks = 0; ks < 10; ks++) {
        short8 kf = *(const short8*)(krow + ks*16);
        sA[kvb] = __builtin_amdgcn_mfma_f32_32x32x16_bf16(kf, qf[ks], sA[kvb], 0, 0, 0);
      }
    }
    __builtin_amdgcn_s_setprio(0);

    float tm = sA[0][0];
#pragma unroll
    for (int kvb = 0; kvb < 2; kvb++)
#pragma unroll
      for (int r = 0; r < 16; r++) tm = fmaxf(tm, sA[kvb][r]);
    tm = fmaxf(tm, __shfl_xor(tm, 32));
    if (!__all(tm - m <= 8.0f)) {
      float nm = fmaxf(m, tm);
      float ef = __expf(m - nm);
      lsum *= ef;
#pragma unroll
      for (int i = 0; i < 9; i++)
#pragma unroll
        for (int r = 0; r < 16; r++) oA[i][r] *= ef;
      m = nm;
    }
    float rs = 0.f;
#pragma unroll
    for (int kvb = 0; kvb < 2; kvb++)
#pragma unroll
      for (int r = 0; r < 16; r++) {
        float p = __expf(sA[kvb][r] - m);
        sA[kvb][r] = p;
        rs += p;
      }
    rs += __shfl_xor(rs, 32);
    lsum += rs;

    unsigned int pk[2][8];
#pragma unroll
    for (int kvb = 0; kvb < 2; kvb++)
#pragma unroll
      for (int k = 0; k < 8; k++) {
        unsigned int r_;
        asm("v_cvt_pk_bf16_f32 %0, %1, %2" : "=v"(r_) : "v"(sA[kvb][2*k]), "v"(sA[kvb][2*k+1]));
        pk[kvb][k] = r_;
      }

#pragma unroll
    for (int s = 0; s < 4; s++) {
      const int n0 = 2*s, n1 = 2*s + 1;
      unsigned int u[4];
#pragma unroll
      for (int p = 0; p < 4; p++) {
        unsigned int Xa = pk[n0 >> 2][(p & 1) + 2*(n0 & 3)];
        unsigned int Xb = pk[n1 >> 2][(p & 1) + 2*(n1 & 3)];
        int src = ql + 32*(p >> 1);
        unsigned int ua = __shfl((int)Xa, src);
        unsigned int ub = __shfl((int)Xb, src);
        u[p] = hb ? ub : ua;
      }
      union { unsigned int uu[4]; short8 s8; } pf;
      pf.uu[0] = u[0]; pf.uu[1] = u[1]; pf.uu[2] = u[2]; pf.uu[3] = u[3];
      __builtin_amdgcn_s_setprio(1);
#pragma unroll
      for (int db = 0; db < 9; db++) {
        int d = ql + 32*db;
        int col = (((2*s + hb) ^ (d & 7)) << 3);
        short8 vf = *(const short8*)(vtbuf + d*KTL + col);
        oA[db] = __builtin_amdgcn_mfma_f32_32x32x16_bf16(vf, pf.s8, oA[db], 0, 0, 0);
      }
      __builtin_amdgcn_s_setprio(0);
    }
    __syncthreads();
  }
#undef STAGE

  float inv = 1.0f / lsum;
  int q = qt*QT + w*32 + ql;
  float* orow = Hf + (((size_t)b*NQL + q)*HN + h)*DV;
#pragma unroll
  for (int db = 0; db < 9; db++)
#pragma unroll
    for (int j = 0; j < 4; j++) {
      int d0 = 32*db + 8*j + 4*hb;
      float4 st = make_float4(oA[db][4*j]*inv, oA[db][4*j+1]*inv,
                              oA[db][4*j+2]*inv, oA[db][4*j+3]*inv);
      *(float4*)(orow + d0) = st;
    }
}

// ---------------- Output projection (4 pos/block, ch-split halves, LDS combine) ----------------
#define HSTR 2308
#define OPOS 4
__global__ __launch_bounds__(256) void proj_o_kernel(
    const float* __restrict__ Hf,
    const float* __restrict__ owT,
    const float* __restrict__ ob_mv, const float* __restrict__ ob_s,
    float* __restrict__ outp)
{
  __shared__ float hL[OPOS*HSTR];      // 36928 B
  __shared__ float pL[128*8];          // seg1 mv partials
  __shared__ float sP[128];            // seg1 scalar partials
  int t = threadIdx.x;
  int p0 = blockIdx.x * OPOS;
  for (int i = t; i < OPOS*2304/4; i += 256) {
    int idx = i*4; int p = idx / 2304; int c = idx - p*2304;
    *(float4*)(hL + p*HSTR + c) = *(const float4*)(Hf + (size_t)(p0 + p)*2304 + c);
  }
  __syncthreads();

  const float* mvT   = owT;            // [y][ch][o]
  const float* s2mvT = owT + 18432;    // jj*16 + o
  const float* mv2sT = owT + 22528;    // ch*32 + si
  const float* s2sT  = owT + 26624;    // jj*32 + si

  int o = t & 15, pp = (t >> 4) & 3, half = (t >> 6) & 1, seg = t >> 7;
  const float* x = hL + pp*HSTR;
  float acc[8];
#pragma unroll
  for (int a = 0; a < 8; a++) acc[a] = 0.f;
  if (half == 0 && seg == 0) acc[0] = ob_mv[o];
  int ch0 = seg*64;

  if (half == 0) {
    for (int ch = ch0; ch < ch0 + 64; ch++) {
      const float* xc = x + (ch >> 4)*288 + (ch & 15)*16;
      float w0 = mvT[0*2048 + ch*16 + o], w1 = mvT[1*2048 + ch*16 + o];
      float w2 = mvT[2*2048 + ch*16 + o];
      float w5 = mvT[5*2048 + ch*16 + o], w6 = mvT[6*2048 + ch*16 + o];
      float x0 = xc[0], x1 = xc[1], x2 = xc[2], x3 = xc[3];
      float x4 = xc[4], x5 = xc[5], x6 = xc[6], x7 = xc[7];
      acc[0] += w0*x0;
      acc[1] += w1*x1 + w5*x0;
      acc[2] += w1*x2;
      acc[3] += w1*x3;
      acc[4] += w1*x4;
      acc[5] += w2*x5 + w6*x2;
      acc[6] += w2*x6 + w6*x3;
      acc[7] += w2*x7 + w6*x4;
    }
    for (int jj = seg*128; jj < seg*128 + 128; jj++)
      acc[0] += s2mvT[jj*16 + o] * x[(jj >> 5)*288 + 256 + (jj & 31)];
  } else {
    for (int ch = ch0; ch < ch0 + 64; ch++) {
      const float* xc = x + (ch >> 4)*288 + (ch & 15)*16 + 8;
      float w2 = mvT[2*2048 + ch*16 + o], w3 = mvT[3*2048 + ch*16 + o];
      float w4 = mvT[4*2048 + ch*16 + o];
      float w7 = mvT[7*2048 + ch*16 + o], w8 = mvT[8*2048 + ch*16 + o];
      float x8 = xc[0], x9 = xc[1], x10 = xc[2], x11 = xc[3];
      float x12 = xc[4], x13 = xc[5], x14 = xc[6], x15 = xc[7];
      acc[0] += w2*x8;
      acc[1] += w2*x9;
      acc[2] += w2*x10;
      acc[3] += w3*x11 + w7*x8;
      acc[4] += w3*x12 + w7*x9;
      acc[5] += w3*x13 + w7*x10;
      acc[6] += w3*x14;
      acc[7] += w4*x15 + w8*x14;
    }
  }

  // scalar outputs (seg-split)
  int si = t & 31, ps = (t >> 5) & 3;
  const float* xs = hL + ps*HSTR;
  float vs = (seg == 0) ? ob_s[si] : 0.f;
  for (int ch = seg*64; ch < seg*64 + 64; ch++)
    vs += mv2sT[ch*32 + si] * xs[(ch >> 4)*288 + (ch & 15)*16];
  for (int jj = seg*128; jj < seg*128 + 128; jj++)
    vs += s2sT[jj*32 + si] * xs[(jj >> 5)*288 + 256 + (jj & 31)];

  if (seg == 1) {
    float* pd = pL + ((half*4 + pp)*16 + o)*8;
#pragma unroll
    for (int a = 0; a < 8; a++) pd[a] = acc[a];
    sP[ps*32 + si] = vs;
  }
  __syncthreads();
  if (seg == 0) {
    const float* pd = pL + ((half*4 + pp)*16 + o)*8;
#pragma unroll
    for (int a = 0; a < 8; a++) acc[a] += pd[a];
    float* od = outp + (size_t)(p0 + pp)*256 + o*16 + half*8;
    *(float4*)(od)     = make_float4(acc[0], acc[1], acc[2], acc[3]);
    *(float4*)(od + 4) = make_float4(acc[4], acc[5], acc[6], acc[7]);
    vs += sP[ps*32 + si];
    float* out_s = outp + (size_t)NB*NQL*256;
    out_s[(size_t)(p0 + ps)*32 + si] = vs;
  }
}

extern "C" void kernel_launch(void* const* d_in, const int* in_sizes, int n_in,
                              void* d_out, int out_size, void* d_ws, size_t ws_size,
                              hipStream_t stream)
{
  const float* mv_kv = (const float*)d_in[0];
  const float* mv_q  = (const float*)d_in[1];
  const float* s_kv  = (const float*)d_in[2];
  const float* s_q   = (const float*)d_in[3];

  ushort* Kf  = (ushort*)d_ws;                          // 4*2048*160   bf16
  ushort* VfT = Kf  + (size_t)NB*NKVL*DQK;              // 4*288*2048   bf16 (baked swizzle)
  ushort* Qf  = VfT + (size_t)NB*DV*NKVL;               // 4*8*2048*160 bf16
  float*  Hf  = (float*)(Qf + (size_t)NB*HN*NQL*DQK);   // 4*2048*8*288 f32
  float*  owT = Hf + (size_t)NB*NQL*HN*DV;              // 34816 f32
  float*  qwT = owT + OWT_SZ;                           // 62720 f32

  prep_w_kernel<<<(OWT_SZ + QWT_SZ + 255)/256, 256, 0, stream>>>(
      (const float*)d_in[22], (const float*)d_in[23],
      (const float*)d_in[25], (const float*)d_in[26], owT,
      (const float*)d_in[4], (const float*)d_in[5], (const float*)d_in[6],
      (const float*)d_in[7], (const float*)d_in[8], (const float*)d_in[9],
      qwT);
  proj_kv_kernel<<<NB*NKVL/KVPOS, 256, 0, stream>>>(mv_kv, s_kv,
      (const float*)d_in[10], (const float*)d_in[11], (const float*)d_in[12],
      (const float*)d_in[13], (const float*)d_in[14], (const float*)d_in[15],
      (const float*)d_in[16], (const float*)d_in[17], (const float*)d_in[18],
      (const float*)d_in[19], (const float*)d_in[20], (const float*)d_in[21],
      Kf, VfT);
  proj_q_kernel<<<NB*NQL/QPOS, 320, 0, stream>>>(mv_q, s_q, qwT, Qf);
  attn_kernel<<<NB*HN*(NQL/QT), 512, 0, stream>>>(Kf, VfT, Qf, Hf);
  proj_o_kernel<<<NB*NQL/OPOS, 256, 0, stream>>>(Hf, owT,
      (const float*)d_in[24], (const float*)d_in[27],
      (float*)d_out);
}

// Round 13
// 335.158 us; speedup vs baseline: 1.1508x; 1.1508x over previous
//
#include <hip/hip_runtime.h>
#include <hip/hip_bf16.h>
#include <math.h>

// Problem constants
#define NB   4
#define NQL  2048
#define NKVL 2048
#define HN   8
#define DQK  160    // qk feature dim
#define DV   288    // v feature dim
#define QT   256    // q rows per block (8 waves x 32)
#define KTL  64     // kv per tile
#define KLP  168    // K LDS row stride (bf16 elems) = 336 B = 21 x 16B chunks

#define SCALE 0.07905694150420949f   // 1/sqrt(160), folded into Q

typedef __attribute__((ext_vector_type(8)))  short short8;
typedef __attribute__((ext_vector_type(4)))  float f32x4;
typedef __attribute__((ext_vector_type(16))) float f32x16;

__constant__ int c_grade[16] = {0,1,1,1,1,2,2,2,2,2,2,3,3,3,3,4};
__constant__ int c_inner[8]  = {0,2,3,4,8,9,10,14};
__constant__ int c_esrc[16]  = {-1,0,-1,-1,-1,2,3,4,-1,-1,-1,8,9,10,-1,14};
__constant__ int c_ey[16]    = {0,5,0,0,0,6,6,6,0,0,0,7,7,7,0,8};

__device__ __forceinline__ ushort f2bf(float v) {
  __hip_bfloat16 h = __float2bfloat16(v);
  union { __hip_bfloat16 b; ushort u; } cv; cv.b = h; return cv.u;
}

// async global->LDS, 16B per lane; LDS dest = uniform base + lane*16
__device__ __forceinline__ void gload16(const void* g, void* l) {
  __builtin_amdgcn_global_load_lds(
      (const __attribute__((address_space(1))) unsigned int*)g,
      (__attribute__((address_space(3))) unsigned int*)l, 16, 0, 0);
}

// ---------------- K/V projection (weight-stationary, 8 pos/block) ----------------
#define KWMV   0
#define KS2MV  2304
#define KMV2S  2816
#define KS2S   3328
#define KBMV   4352
#define KBS    4368
#define VWMV   4400
#define VS2MV  6704
#define VMV2S  7216
#define VS2S   7728
#define VBMV   8752
#define VBS    8768
#define WLSZ   8800
#define XSTR   289   // pos stride in xL
#define OSTR   456   // pos stride in oL (ushort)
#define KVPOS  8

__device__ __forceinline__ void kv_accum(const float* wL, const float* xL,
                                         int f, float acc[KVPOS]) {
  if (f < 160) {
    if (f < 128) {                      // K mv-feature
      int c = f >> 3, a = c_inner[f & 7], y = c_grade[a];
      float bias = (a == 0) ? wL[KBMV + c] : 0.f;
#pragma unroll
      for (int p = 0; p < KVPOS; p++) acc[p] = bias;
      for (int ci = 0; ci < 16; ci++) {
        float w = wL[KWMV + (c*16 + ci)*9 + y];
#pragma unroll
        for (int p = 0; p < KVPOS; p++) acc[p] += w * xL[p*XSTR + ci*16 + a];
      }
      if (a == 0) {
        for (int i2 = 0; i2 < 32; i2++) {
          float w = wL[KS2MV + c*32 + i2];
#pragma unroll
          for (int p = 0; p < KVPOS; p++) acc[p] += w * xL[p*XSTR + 256 + i2];
        }
      }
    } else {                            // K scalar
      int si = f - 128;
      float bias = wL[KBS + si];
#pragma unroll
      for (int p = 0; p < KVPOS; p++) acc[p] = bias;
      for (int ci = 0; ci < 16; ci++) {
        float w = wL[KMV2S + si*16 + ci];
#pragma unroll
        for (int p = 0; p < KVPOS; p++) acc[p] += w * xL[p*XSTR + ci*16];
      }
      for (int i2 = 0; i2 < 32; i2++) {
        float w = wL[KS2S + si*32 + i2];
#pragma unroll
        for (int p = 0; p < KVPOS; p++) acc[p] += w * xL[p*XSTR + 256 + i2];
      }
    }
  } else {
    int g = f - 160;
    if (g < 256) {                      // V mv-feature
      int c = g >> 4, a = g & 15, y = c_grade[a];
      float bias = (a == 0) ? wL[VBMV + c] : 0.f;
#pragma unroll
      for (int p = 0; p < KVPOS; p++) acc[p] = bias;
      for (int ci = 0; ci < 16; ci++) {
        float w = wL[VWMV + (c*16 + ci)*9 + y];
#pragma unroll
        for (int p = 0; p < KVPOS; p++) acc[p] += w * xL[p*XSTR + ci*16 + a];
      }
      int sa = c_esrc[a];
      if (sa >= 0) {
        int ey = c_ey[a];
        for (int ci = 0; ci < 16; ci++) {
          float w = wL[VWMV + (c*16 + ci)*9 + ey];
#pragma unroll
          for (int p = 0; p < KVPOS; p++) acc[p] += w * xL[p*XSTR + ci*16 + sa];
        }
      }
      if (a == 0) {
        for (int i2 = 0; i2 < 32; i2++) {
          float w = wL[VS2MV + c*32 + i2];
#pragma unroll
          for (int p = 0; p < KVPOS; p++) acc[p] += w * xL[p*XSTR + 256 + i2];
        }
      }
    } else {                            // V scalar
      int si = g - 256;
      float bias = wL[VBS + si];
#pragma unroll
      for (int p = 0; p < KVPOS; p++) acc[p] = bias;
      for (int ci = 0; ci < 16; ci++) {
        float w = wL[VMV2S + si*16 + ci];
#pragma unroll
        for (int p = 0; p < KVPOS; p++) acc[p] += w * xL[p*XSTR + ci*16];
      }
      for (int i2 = 0; i2 < 32; i2++) {
        float w = wL[VS2S + si*32 + i2];
#pragma unroll
        for (int p = 0; p < KVPOS; p++) acc[p] += w * xL[p*XSTR + 256 + i2];
      }
    }
  }
}

__global__ __launch_bounds__(256) void proj_kv_kernel(
    const float* __restrict__ mv_kv, const float* __restrict__ s_kv,
    const float* __restrict__ kw_mv, const float* __restrict__ kw_s2mv, const float* __restrict__ kb_mv,
    const float* __restrict__ kw_mv2s, const float* __restrict__ kw_s2s, const float* __restrict__ kb_s,
    const float* __restrict__ vw_mv, const float* __restrict__ vw_s2mv, const float* __restrict__ vb_mv,
    const float* __restrict__ vw_mv2s, const float* __restrict__ vw_s2s, const float* __restrict__ vb_s,
    ushort* __restrict__ Kf, ushort* __restrict__ VfT)
{
  __shared__ float wL[WLSZ];
  __shared__ float xL[KVPOS*XSTR];
  int t = threadIdx.x;
  for (int i = t; i < 2304; i += 256) wL[KWMV + i] = kw_mv[i];
  for (int i = t; i < 512;  i += 256) wL[KS2MV + i] = kw_s2mv[i];
  for (int i = t; i < 512;  i += 256) wL[KMV2S + i] = kw_mv2s[i];
  for (int i = t; i < 1024; i += 256) wL[KS2S + i] = kw_s2s[i];
  if (t < 16) wL[KBMV + t] = kb_mv[t];
  if (t < 32) wL[KBS + t] = kb_s[t];
  for (int i = t; i < 2304; i += 256) wL[VWMV + i] = vw_mv[i];
  for (int i = t; i < 512;  i += 256) wL[VS2MV + i] = vw_s2mv[i];
  for (int i = t; i < 512;  i += 256) wL[VMV2S + i] = vw_mv2s[i];
  for (int i = t; i < 1024; i += 256) wL[VS2S + i] = vw_s2s[i];
  if (t < 16) wL[VBMV + t] = vb_mv[t];
  if (t < 32) wL[VBS + t] = vb_s[t];

  int p0 = blockIdx.x * KVPOS;
  for (int i = t; i < KVPOS*256; i += 256) {
    int p = i >> 8, c = i & 255;
    xL[p*XSTR + c] = mv_kv[(size_t)(p0 + p)*256 + c];
  }
  if (t < KVPOS*32) {
    int p = t >> 5, c = t & 31;
    xL[p*XSTR + 256 + c] = s_kv[(size_t)(p0 + p)*32 + c];
  }
  __syncthreads();

  float acc0[KVPOS], acc1[KVPOS];
  kv_accum(wL, xL, t, acc0);
  if (t < 192) kv_accum(wL, xL, 256 + t, acc1);
  __syncthreads();

  ushort* oL = (ushort*)xL;
#pragma unroll
  for (int p = 0; p < KVPOS; p++) oL[p*OSTR + t] = f2bf(acc0[p]);
  if (t < 192) {
#pragma unroll
    for (int p = 0; p < KVPOS; p++) oL[p*OSTR + 256 + t] = f2bf(acc1[p]);
  }
  __syncthreads();

  int b = p0 >> 11, kv0 = p0 & 2047;
  for (int it = 0; it < 3; it++) {
    int j = t + it*256;
    if (j < KVPOS*80) {
      int p = j / 80, fp = j - p*80;
      uint u = (uint)oL[p*OSTR + 2*fp] | ((uint)oL[p*OSTR + 2*fp + 1] << 16);
      *(uint*)(Kf + (size_t)(p0 + p)*DQK + 2*fp) = u;
    }
  }
  // V^T with chunk-XOR baked into the GLOBAL layout
  for (int it = 0; it < 5; it++) {
    int j = t + it*256;
    if (j < DV*(KVPOS/2)) {
      int g = j >> 2, pp = j & 3;
      uint u = (uint)oL[(2*pp)*OSTR + 160 + g] | ((uint)oL[(2*pp+1)*OSTR + 160 + g] << 16);
      int kv = kv0 + 2*pp;
      int pos = (kv & ~63) + ((((kv >> 3) & 7) ^ (g & 7)) << 3) + (kv & 7);
      *(uint*)(VfT + ((size_t)b*DV + g)*NKVL + pos) = u;
    }
  }
}

// ---------------- fused weight-prep (O transpose + Q transpose) ----------------
#define OWT_SZ 34816
#define QWT_MV 0
#define QWT_S  20480
#define QBT    61440
#define QWT_SZ 62720
__global__ __launch_bounds__(256) void prep_w_kernel(
    const float* __restrict__ ow_mv, const float* __restrict__ ow_s2mv,
    const float* __restrict__ ow_mv2s, const float* __restrict__ ow_s2s,
    float* __restrict__ owT,
    const float* __restrict__ qw_mv, const float* __restrict__ qw_s2mv, const float* __restrict__ qb_mv,
    const float* __restrict__ qw_mv2s, const float* __restrict__ qw_s2s, const float* __restrict__ qb_s,
    float* __restrict__ qwT)
{
  int i = blockIdx.x*256 + threadIdx.x;
  if (i < OWT_SZ) {
    if (i < 18432) {
      int y = i / 2048, r = i & 2047, ch = r >> 4, o = r & 15;
      owT[i] = ow_mv[(size_t)(o*128 + ch)*9 + y];
    } else if (i < 22528) {
      int r = i - 18432, jj = r >> 4, o = r & 15;
      owT[i] = ow_s2mv[o*256 + jj];
    } else if (i < 26624) {
      int r = i - 22528, ch = r >> 5, si = r & 31;
      owT[i] = ow_mv2s[si*128 + ch];
    } else {
      int r = i - 26624, jj = r >> 5, si = r & 31;
      owT[i] = ow_s2s[si*256 + jj];
    }
    return;
  }
  int j = i - OWT_SZ;
  if (j >= QWT_SZ) return;
  if (j < QWT_S) {
    int ci = j / 1280, r = j - ci*1280, h = r / 160, f0 = r - h*160;
    float v;
    if (f0 < 128) {
      int c = f0 >> 3, a = c_inner[f0 & 7], y = c_grade[a];
      v = qw_mv[((c*HN + h)*16 + ci)*9 + y];
    } else {
      v = qw_mv2s[((f0 - 128)*HN + h)*16 + ci];
    }
    qwT[j] = v;
  } else if (j < QBT) {
    int k = j - QWT_S;
    int i2 = k / 1280, r = k - i2*1280, h = r / 160, f0 = r - h*160;
    float v;
    if (f0 < 128) {
      int c = f0 >> 3, a = c_inner[f0 & 7];
      v = (a == 0) ? qw_s2mv[(c*HN + h)*32 + i2] : 0.f;
    } else {
      v = qw_s2s[((f0 - 128)*HN + h)*32 + i2];
    }
    qwT[j] = v;
  } else {
    int r = j - QBT, h = r / 160, f0 = r - h*160;
    float v;
    if (f0 < 128) {
      int c = f0 >> 3, a = c_inner[f0 & 7];
      v = (a == 0) ? qb_mv[c*HN + h] : 0.f;
    } else {
      v = qb_s[(f0 - 128)*HN + h];
    }
    qwT[j] = v;
  }
}

// ---------------- Q projection (coalesced transposed weights, 8 pos/block) ----------------
#define QPOS 8
__global__ __launch_bounds__(320) void proj_q_kernel(
    const float* __restrict__ mv_q, const float* __restrict__ s_q,
    const float* __restrict__ qwT,
    ushort* __restrict__ Qf)
{
  __shared__ float xL[QPOS*XSTR];
  int t = threadIdx.x;
  int p0 = blockIdx.x * QPOS;
  for (int i = t; i < QPOS*256; i += 320) {
    int p = i >> 8, c = i & 255;
    xL[p*XSTR + c] = mv_q[(size_t)(p0 + p)*256 + c];
  }
  if (t < QPOS*32) {
    int p = t >> 5, c = t & 31;
    xL[p*XSTR + 256 + c] = s_q[(size_t)(p0 + p)*32 + c];
  }
  __syncthreads();

  int f0 = t % 160;
  int h0 = t / 160;
  int a = (f0 < 128) ? c_inner[f0 & 7] : 0;

  float acc[4][QPOS];
#pragma unroll
  for (int k = 0; k < 4; k++) {
    float bv = qwT[QBT + (h0 + 2*k)*160 + f0];
#pragma unroll
    for (int p = 0; p < QPOS; p++) acc[k][p] = bv;
  }
  for (int ci = 0; ci < 16; ci++) {
    float w0 = qwT[QWT_MV + (ci*HN + h0    )*160 + f0];
    float w1 = qwT[QWT_MV + (ci*HN + h0 + 2)*160 + f0];
    float w2 = qwT[QWT_MV + (ci*HN + h0 + 4)*160 + f0];
    float w3 = qwT[QWT_MV + (ci*HN + h0 + 6)*160 + f0];
#pragma unroll
    for (int p = 0; p < QPOS; p++) {
      float xv = xL[p*XSTR + ci*16 + a];
      acc[0][p] += w0*xv; acc[1][p] += w1*xv;
      acc[2][p] += w2*xv; acc[3][p] += w3*xv;
    }
  }
  for (int i2 = 0; i2 < 32; i2++) {
    float w0 = qwT[QWT_S + (i2*HN + h0    )*160 + f0];
    float w1 = qwT[QWT_S + (i2*HN + h0 + 2)*160 + f0];
    float w2 = qwT[QWT_S + (i2*HN + h0 + 4)*160 + f0];
    float w3 = qwT[QWT_S + (i2*HN + h0 + 6)*160 + f0];
#pragma unroll
    for (int p = 0; p < QPOS; p++) {
      float xv = xL[p*XSTR + 256 + i2];
      acc[0][p] += w0*xv; acc[1][p] += w1*xv;
      acc[2][p] += w2*xv; acc[3][p] += w3*xv;
    }
  }

  int b = p0 >> 11, q0 = p0 & 2047;
#pragma unroll
  for (int k = 0; k < 4; k++) {
    int h = h0 + 2*k;
    ushort* qdst = Qf + ((size_t)(b*HN + h)*NQL + q0)*DQK + f0;
#pragma unroll
    for (int p = 0; p < QPOS; p++)
      qdst[p*DQK] = f2bf(acc[k][p] * SCALE);
  }
}

// ---------------- MFMA flash attention (unchanged from round 11) ----------------
__global__ __launch_bounds__(512, 2) void attn_kernel(
    const ushort* __restrict__ Kf,   // [b][2048][160] row-major
    const ushort* __restrict__ VfT,  // [b][288][2048] chunk-XOR pre-baked
    const ushort* __restrict__ Qf,   // [bh][2048][160] (scaled)
    float* __restrict__ Hf)          // [b][q][h][288]
{
  __shared__ ushort kL[2][KTL*KLP];
  __shared__ ushort vtL[2][DV*KTL];

  const int NT = NQL/QT;             // 8; grid = 256 blocks (1/CU)
  int bid = blockIdx.x;
  int swz = (bid & 7) * 32 + (bid >> 3);
  int bh = swz / NT;
  int qt = swz - bh*NT;
  int b = bh >> 3, h = bh & 7;
  int t = threadIdx.x, w = t >> 6, l = t & 63;
  int ql = l & 31, hb = l >> 5;

  const ushort* kb = Kf  + (size_t)b*NKVL*DQK;
  const ushort* vb = VfT + (size_t)b*DV*NKVL;

  const ushort* qrow = Qf + ((size_t)bh*NQL + (size_t)qt*QT + w*32 + ql)*DQK + hb*8;
  short8 qf[10];
#pragma unroll
  for (int ks = 0; ks < 10; ks++)
    qf[ks] = *(const short8*)(qrow + ks*16);

  f32x16 oA[9];
#pragma unroll
  for (int i = 0; i < 9; i++) oA[i] = (f32x16)(0.f);
  float m = -INFINITY, lsum = 0.f;

#define STAGE(KT, BUF) do {                                            \
    const ushort* kg_ = kb + (size_t)(KT)*KTL*DQK;                     \
    char* kd_ = (char*)&kL[BUF][0];                                    \
    for (int c_ = w; c_ < 21; c_ += 8) {                               \
      int off_ = c_*1024 + l*16;                                       \
      int row_ = off_ / 336;                                           \
      int bc_  = off_ - row_*336;                                      \
      const ushort* ga_ = kg_ + row_*DQK + ((bc_ < 320) ? (bc_ >> 1) : 0); \
      gload16(ga_, kd_ + c_*1024);                                     \
    }                                                                  \
    const ushort* vg_ = vb + (size_t)(KT)*KTL;                         \
    char* vd_ = (char*)&vtL[BUF][0];                                   \
    for (int c_ = w; c_ < 36; c_ += 8) {                               \
      int off_ = c_*1024 + l*16;                                       \
      int d_  = off_ >> 7;                                             \
      int bc_ = off_ & 127;                                            \
      const ushort* ga_ = vg_ + (size_t)d_*NKVL + (bc_ >> 1);          \
      gload16(ga_, vd_ + c_*1024);                                     \
    }                                                                  \
  } while (0)

  STAGE(0, 0);
  __syncthreads();

  for (int kt = 0; kt < NKVL/KTL; kt++) {
    int cur = kt & 1;
    if (kt + 1 < NKVL/KTL) STAGE(kt + 1, cur ^ 1);

    const ushort* kbuf  = &kL[cur][0];
    const ushort* vtbuf = &vtL[cur][0];

    f32x16 sA[2];
    __builtin_amdgcn_s_setprio(1);
#pragma unroll
    for (int kvb = 0; kvb < 2; kvb++) {
      sA[kvb] = (f32x16)(0.f);
      const ushort* krow = kbuf + (ql + 32*kvb)*KLP + hb*8;
#pragma unroll
      for (int ks = 0; ks < 10; ks++) {
        short8 kf = *(const short8*)(krow + ks*16);
        sA[kvb] = __builtin_amdgcn_mfma_f32_32x32x16_bf16(kf, qf[ks], sA[kvb], 0, 0, 0);
      }
    }
    __builtin_amdgcn_s_setprio(0);

    float tm = sA[0][0];
#pragma unroll
    for (int kvb = 0; kvb < 2; kvb++)
#pragma unroll
      for (int r = 0; r < 16; r++) tm = fmaxf(tm, sA[kvb][r]);
    tm = fmaxf(tm, __shfl_xor(tm, 32));
    if (!__all(tm - m <= 8.0f)) {
      float nm = fmaxf(m, tm);
      float ef = __expf(m - nm);
      lsum *= ef;
#pragma unroll
      for (int i = 0; i < 9; i++)
#pragma unroll
        for (int r = 0; r < 16; r++) oA[i][r] *= ef;
      m = nm;
    }
    float rs = 0.f;
#pragma unroll
    for (int kvb = 0; kvb < 2; kvb++)
#pragma unroll
      for (int r = 0; r < 16; r++) {
        float p = __expf(sA[kvb][r] - m);
        sA[kvb][r] = p;
        rs += p;
      }
    rs += __shfl_xor(rs, 32);
    lsum += rs;

    unsigned int pk[2][8];
#pragma unroll
    for (int kvb = 0; kvb < 2; kvb++)
#pragma unroll
      for (int k = 0; k < 8; k++) {
        unsigned int r_;
        asm("v_cvt_pk_bf16_f32 %0, %1, %2" : "=v"(r_) : "v"(sA[kvb][2*k]), "v"(sA[kvb][2*k+1]));
        pk[kvb][k] = r_;
      }

#pragma unroll
    for (int s = 0; s < 4; s++) {
      const int n0 = 2*s, n1 = 2*s + 1;
      unsigned int u[4];
#pragma unroll
      for (int p = 0; p < 4; p++) {
        unsigned int Xa = pk[n0 >> 2][(p & 1) + 2*(n0 & 3)];
        unsigned int Xb = pk[n1 >> 2][(p & 1) + 2*(n1 & 3)];
        int src = ql + 32*(p >> 1);
        unsigned int ua = __shfl((int)Xa, src);
        unsigned int ub = __shfl((int)Xb, src);
        u[p] = hb ? ub : ua;
      }
      union { unsigned int uu[4]; short8 s8; } pf;
      pf.uu[0] = u[0]; pf.uu[1] = u[1]; pf.uu[2] = u[2]; pf.uu[3] = u[3];
      __builtin_amdgcn_s_setprio(1);
#pragma unroll
      for (int db = 0; db < 9; db++) {
        int d = ql + 32*db;
        int col = (((2*s + hb) ^ (d & 7)) << 3);
        short8 vf = *(const short8*)(vtbuf + d*KTL + col);
        oA[db] = __builtin_amdgcn_mfma_f32_32x32x16_bf16(vf, pf.s8, oA[db], 0, 0, 0);
      }
      __builtin_amdgcn_s_setprio(0);
    }
    __syncthreads();
  }
#undef STAGE

  float inv = 1.0f / lsum;
  int q = qt*QT + w*32 + ql;
  float* orow = Hf + (((size_t)b*NQL + q)*HN + h)*DV;
#pragma unroll
  for (int db = 0; db < 9; db++)
#pragma unroll
    for (int j = 0; j < 4; j++) {
      int d0 = 32*db + 8*j + 4*hb;
      float4 st = make_float4(oA[db][4*j]*inv, oA[db][4*j+1]*inv,
                              oA[db][4*j+2]*inv, oA[db][4*j+3]*inv);
      *(float4*)(orow + d0) = st;
    }
}

// ---------------- Output projection (weight-amortized: 8 pos/thread) ----------------
// 512 threads: mv phase thread = (o = t&15, a = (t>>4)&15, seg = t>>8), 64 ch/seg, acc[8].
// s2mv/mv2s/s2s in a segmented phase (8 segs x 48 outs), partials in sP, combined after sync.
#define HSTR2 2308
#define OPOS2 8
__global__ __launch_bounds__(512) void proj_o_kernel(
    const float* __restrict__ Hf,
    const float* __restrict__ owT,
    const float* __restrict__ ob_mv, const float* __restrict__ ob_s,
    float* __restrict__ outp)
{
  __shared__ float hL[OPOS2*HSTR2];    // 73856 B
  __shared__ float pL[256*8];          // mv partials/final (oa x p), 8192 B
  __shared__ float sP[8*48*8];         // [seg][u][p] partials, 12288 B
  int t = threadIdx.x;
  int p0 = blockIdx.x * OPOS2;
  for (int i = t; i < OPOS2*2304/4; i += 512) {
    int idx = i*4; int p = idx / 2304; int c = idx - p*2304;
    *(float4*)(hL + p*HSTR2 + c) = *(const float4*)(Hf + (size_t)(p0 + p)*2304 + c);
  }
  __syncthreads();

  const float* mvT   = owT;            // y*2048 + ch*16 + o
  const float* s2mvT = owT + 18432;    // jj*16 + o
  const float* mv2sT = owT + 22528;    // ch*32 + si
  const float* s2sT  = owT + 26624;    // jj*32 + si

  // ---- mv phase ----
  int o = t & 15, a = (t >> 4) & 15, seg = t >> 8;
  int oa = o*16 + a;
  int y = c_grade[a], sa = c_esrc[a], ey = c_ey[a];
  float acc[OPOS2];
#pragma unroll
  for (int p = 0; p < OPOS2; p++) acc[p] = 0.f;
  for (int ch = seg*64; ch < seg*64 + 64; ch++) {
    int xb = (ch >> 4)*288 + (ch & 15)*16;
    float w1 = mvT[y*2048 + ch*16 + o];
#pragma unroll
    for (int p = 0; p < OPOS2; p++) acc[p] += w1 * hL[p*HSTR2 + xb + a];
    if (sa >= 0) {
      float w2 = mvT[ey*2048 + ch*16 + o];
#pragma unroll
      for (int p = 0; p < OPOS2; p++) acc[p] += w2 * hL[p*HSTR2 + xb + sa];
    }
  }
  if (seg == 1) {
#pragma unroll
    for (int p = 0; p < OPOS2; p++) pL[oa*8 + p] = acc[p];
  }
  __syncthreads();
  if (seg == 0) {
#pragma unroll
    for (int p = 0; p < OPOS2; p++) acc[p] += pL[oa*8 + p];
  }

  // ---- segmented scalar + s2mv phase (8 segs x 48 outs) ----
  int v = t >> 6, u = t & 63;          // v = 0..7, u = 0..63
  float sacc[OPOS2];
#pragma unroll
  for (int p = 0; p < OPOS2; p++) sacc[p] = 0.f;
  if (u < 32) {                        // scalar out si = u
    int si = u;
    for (int ch = v*16; ch < v*16 + 16; ch++) {
      float w = mv2sT[ch*32 + si];
      int xb = (ch >> 4)*288 + (ch & 15)*16;
#pragma unroll
      for (int p = 0; p < OPOS2; p++) sacc[p] += w * hL[p*HSTR2 + xb];
    }
    for (int jj = v*32; jj < v*32 + 32; jj++) {
      float w = s2sT[jj*32 + si];
      int xb = (jj >> 5)*288 + 256 + (jj & 31);
#pragma unroll
      for (int p = 0; p < OPOS2; p++) sacc[p] += w * hL[p*HSTR2 + xb];
    }
  } else if (u < 48) {                 // s2mv partial for o2 = u - 32 (into mv a=0)
    int o2 = u - 32;
    for (int jj = v*32; jj < v*32 + 32; jj++) {
      float w = s2mvT[jj*16 + o2];
      int xb = (jj >> 5)*288 + 256 + (jj & 31);
#pragma unroll
      for (int p = 0; p < OPOS2; p++) sacc[p] += w * hL[p*HSTR2 + xb];
    }
  }
  if (u < 48) {
#pragma unroll
    for (int p = 0; p < OPOS2; p++) sP[(v*48 + u)*8 + p] = sacc[p];
  }
  __syncthreads();

  // ---- final combine + staged coalesced stores ----
  if (seg == 0) {
    if (a == 0) {                      // add s2mv partials + bias
      float bv = ob_mv[o];
#pragma unroll
      for (int p = 0; p < OPOS2; p++) {
        float s = bv;
#pragma unroll
        for (int vv = 0; vv < 8; vv++) s += sP[(vv*48 + 32 + o)*8 + p];
        acc[p] += s;
      }
    }
#pragma unroll
    for (int p = 0; p < OPOS2; p++) pL[oa*8 + p] = acc[p];
  }
  __syncthreads();
  // mv outs: 2048 floats, coalesced
  for (int i = t; i < 256*OPOS2; i += 512) {
    int p = i >> 8, c = i & 255;
    outp[(size_t)(p0 + p)*256 + c] = pL[c*8 + p];
  }
  // scalar outs
  if (t >= 256 && t < 256 + 32) {
    int si = t - 256;
    float bv = ob_s[si];
    float* out_s = outp + (size_t)NB*NQL*256;
#pragma unroll
    for (int p = 0; p < OPOS2; p++) {
      float s = bv;
#pragma unroll
      for (int vv = 0; vv < 8; vv++) s += sP[(vv*48 + si)*8 + p];
      out_s[(size_t)(p0 + p)*32 + si] = s;
    }
  }
}

extern "C" void kernel_launch(void* const* d_in, const int* in_sizes, int n_in,
                              void* d_out, int out_size, void* d_ws, size_t ws_size,
                              hipStream_t stream)
{
  const float* mv_kv = (const float*)d_in[0];
  const float* mv_q  = (const float*)d_in[1];
  const float* s_kv  = (const float*)d_in[2];
  const float* s_q   = (const float*)d_in[3];

  ushort* Kf  = (ushort*)d_ws;                          // 4*2048*160   bf16
  ushort* VfT = Kf  + (size_t)NB*NKVL*DQK;              // 4*288*2048   bf16 (baked swizzle)
  ushort* Qf  = VfT + (size_t)NB*DV*NKVL;               // 4*8*2048*160 bf16
  float*  Hf  = (float*)(Qf + (size_t)NB*HN*NQL*DQK);   // 4*2048*8*288 f32
  float*  owT = Hf + (size_t)NB*NQL*HN*DV;              // 34816 f32
  float*  qwT = owT + OWT_SZ;                           // 62720 f32

  prep_w_kernel<<<(OWT_SZ + QWT_SZ + 255)/256, 256, 0, stream>>>(
      (const float*)d_in[22], (const float*)d_in[23],
      (const float*)d_in[25], (const float*)d_in[26], owT,
      (const float*)d_in[4], (const float*)d_in[5], (const float*)d_in[6],
      (const float*)d_in[7], (const float*)d_in[8], (const float*)d_in[9],
      qwT);
  proj_kv_kernel<<<NB*NKVL/KVPOS, 256, 0, stream>>>(mv_kv, s_kv,
      (const float*)d_in[10], (const float*)d_in[11], (const float*)d_in[12],
      (const float*)d_in[13], (const float*)d_in[14], (const float*)d_in[15],
      (const float*)d_in[16], (const float*)d_in[17], (const float*)d_in[18],
      (const float*)d_in[19], (const float*)d_in[20], (const float*)d_in[21],
      Kf, VfT);
  proj_q_kernel<<<NB*NQL/QPOS, 320, 0, stream>>>(mv_q, s_q, qwT, Qf);
  attn_kernel<<<NB*HN*(NQL/QT), 512, 0, stream>>>(Kf, VfT, Qf, Hf);
  proj_o_kernel<<<NB*NQL/OPOS2, 512, 0, stream>>>(Hf, owT,
      (const float*)d_in[24], (const float*)d_in[27],
      (float*)d_out);
}